// Round 3
// baseline (1387.785 us; speedup 1.0000x reference)
//
#include <hip/hip_runtime.h>

// GCN 2-layer: per layer h = X@W; out[i] = b + dinv[i]^2*h[i] + sum_{e:dst=i} dinv[src]*dinv[i]*h[src]
// N=100000 nodes, E=1200000 edges, C=64 channels, fp32 throughout.
// CSR-by-dst build (histogram + scan + scatter of PACKED (src,norm) int2 pairs),
// then gather-aggregate (wave per node, lane per channel). No float atomics.
// R3: gemm rewritten as 64x64 tile, 4x4 outputs/thread (16 acc), 8 b128 LDS reads
//     per 64 FMA, launch_bounds(256,4) -> target >=4 blocks/CU occupancy.
//     (R2 version was 256 VGPR / 9% occupancy / latency-bound at 77us.)

#define NCH 64
#define XS_STRIDE 68  // 64 + 4 pad: keeps b128 16B alignment; 4-row spacing -> bank+16 (2-way, free)

// counts[d] = #edges with dst==d
__global__ void hist_kernel(const int* __restrict__ dst, int* __restrict__ counts, int E) {
    int e = blockIdx.x * blockDim.x + threadIdx.x;
    if (e < E) atomicAdd(&counts[dst[e]], 1);
}

// ---------------- exclusive scan (3-phase), chunk = 1024; dinv fused ----------------
__global__ __launch_bounds__(256) void scanA_kernel(const int* __restrict__ counts,
                                                    int* __restrict__ rowp,
                                                    int* __restrict__ bsums,
                                                    float* __restrict__ dinv, int n) {
    __shared__ int sh[256];
    int tid = threadIdx.x;
    int base = blockIdx.x * 1024;
    int v[4];
    int ts = 0;
#pragma unroll
    for (int j = 0; j < 4; j++) {
        int idx = base + tid * 4 + j;
        int c = (idx < n) ? counts[idx] : 0;
        v[j] = c; ts += c;
        if (idx < n) dinv[idx] = rsqrtf((float)(c + 1));  // +1 self loop
    }
    sh[tid] = ts; __syncthreads();
    for (int off = 1; off < 256; off <<= 1) {
        int t = (tid >= off) ? sh[tid - off] : 0;
        __syncthreads();
        sh[tid] += t;
        __syncthreads();
    }
    int run = sh[tid] - ts;  // exclusive offset within chunk
#pragma unroll
    for (int j = 0; j < 4; j++) {
        run += v[j];
        int idx = base + tid * 4 + j;
        if (idx < n) rowp[idx + 1] = run;  // inclusive-within-chunk at [idx+1]
    }
    if (tid == 255) bsums[blockIdx.x] = sh[255];
}

__global__ __launch_bounds__(128) void scanB_kernel(int* __restrict__ bsums, int nb) {
    __shared__ int sh[128];
    int tid = threadIdx.x;
    int v = (tid < nb) ? bsums[tid] : 0;
    sh[tid] = v; __syncthreads();
    for (int off = 1; off < 128; off <<= 1) {
        int t = (tid >= off) ? sh[tid - off] : 0;
        __syncthreads();
        sh[tid] += t;
        __syncthreads();
    }
    if (tid < nb) bsums[tid] = sh[tid] - v;  // exclusive chunk offsets
}

__global__ void scanC_kernel(int* __restrict__ rowp, const int* __restrict__ bsums, int n) {
    int i = blockIdx.x * blockDim.x + threadIdx.x;
    if (i < n) {
        rowp[i + 1] += bsums[i >> 10];
        if (i == 0) rowp[0] = 0;
    }
}

// scatter edges into CSR buckets as packed (src, norm) pairs — single 8B store/edge
__global__ void scatter_kernel(const int* __restrict__ src, const int* __restrict__ dst,
                               const int* __restrict__ rowp, int* __restrict__ cursor,
                               const float* __restrict__ dinv,
                               int2* __restrict__ cpair, int E) {
    int e = blockIdx.x * blockDim.x + threadIdx.x;
    if (e < E) {
        int s = src[e], d = dst[e];
        int pos = rowp[d] + atomicAdd(&cursor[d], 1);
        cpair[pos] = make_int2(s, __float_as_int(dinv[s] * dinv[d]));
    }
}

// ---------------- H = X @ W  (K=64, fp32 VALU) ----------------
// 64x64 tile per block; 256 threads as 16x16; each thread: 4 rows x 4 cols (16 acc).
// Per k4-step: 4 b128 X reads + 4 b128 W reads per 64 FMAs.
__global__ __launch_bounds__(256, 4) void gemm64_kernel(const float* __restrict__ X,
                                                        const float* __restrict__ W,
                                                        float* __restrict__ H, int nrows) {
    __shared__ float Xs[64 * XS_STRIDE];
    __shared__ float Ws[64 * 64];
    int tid = threadIdx.x;
    int row0 = blockIdx.x * 64;

    // stage W (4096 floats): 4 float4/thread, coalesced
    {
        const float4* W4 = (const float4*)W;
#pragma unroll
        for (int i = 0; i < 4; i++) {
            int idx = tid + 256 * i;           // float4 index
            float4 v = W4[idx];
            int r = idx >> 4, kc = (idx & 15) << 2;
            *(float4*)&Ws[r * 64 + kc] = v;
        }
    }
    // stage X tile (64 rows x 64): 4 float4/thread, coalesced; padded stride in LDS
    {
        const float4* X4 = (const float4*)(X + (size_t)row0 * NCH);
#pragma unroll
        for (int i = 0; i < 4; i++) {
            int idx = tid + 256 * i;
            int r = idx >> 4, kc = (idx & 15) << 2;
            if (row0 + r < nrows)
                *(float4*)&Xs[r * XS_STRIDE + kc] = X4[idx];
        }
    }
    __syncthreads();

    int c  = (tid & 15) << 2;   // col base
    int r0 = (tid >> 4) << 2;   // block-local row base

    float4 acc[4];
#pragma unroll
    for (int i = 0; i < 4; i++) acc[i] = make_float4(0.f, 0.f, 0.f, 0.f);

#pragma unroll
    for (int k4 = 0; k4 < 16; k4++) {
        float4 wv[4], xv[4];
#pragma unroll
        for (int j = 0; j < 4; j++) wv[j] = *(const float4*)&Ws[(k4 * 4 + j) * 64 + c];
#pragma unroll
        for (int i = 0; i < 4; i++) xv[i] = *(const float4*)&Xs[(r0 + i) * XS_STRIDE + k4 * 4];
#pragma unroll
        for (int i = 0; i < 4; i++) {
            acc[i].x += xv[i].x * wv[0].x + xv[i].y * wv[1].x + xv[i].z * wv[2].x + xv[i].w * wv[3].x;
            acc[i].y += xv[i].x * wv[0].y + xv[i].y * wv[1].y + xv[i].z * wv[2].y + xv[i].w * wv[3].y;
            acc[i].z += xv[i].x * wv[0].z + xv[i].y * wv[1].z + xv[i].z * wv[2].z + xv[i].w * wv[3].z;
            acc[i].w += xv[i].x * wv[0].w + xv[i].y * wv[1].w + xv[i].z * wv[2].w + xv[i].w * wv[3].w;
        }
    }

#pragma unroll
    for (int i = 0; i < 4; i++) {
        int row = row0 + r0 + i;
        if (row < nrows) *(float4*)&H[(size_t)row * NCH + c] = acc[i];
    }
}

// ---------------- gather-aggregate: wave per node, lane per channel ----------------
// unroll x4, 4 independent accumulators -> 4 gathers in flight
__global__ __launch_bounds__(256) void aggregate_kernel(const float* __restrict__ H,
                                                        const int* __restrict__ rowp,
                                                        const int2* __restrict__ cpair,
                                                        const float* __restrict__ dinv,
                                                        const float* __restrict__ bias,
                                                        float* __restrict__ out,
                                                        int n, int do_relu) {
    int node = blockIdx.x * 4 + (threadIdx.x >> 6);
    int lane = threadIdx.x & 63;
    if (node >= n) return;
    float di = dinv[node];
    float a0 = bias[lane] + di * di * H[(size_t)node * NCH + lane];
    float a1 = 0.f, a2 = 0.f, a3 = 0.f;
    int e = rowp[node];
    int end = rowp[node + 1];
    for (; e + 3 < end; e += 4) {
        int2 p0 = cpair[e];
        int2 p1 = cpair[e + 1];
        int2 p2 = cpair[e + 2];
        int2 p3 = cpair[e + 3];
        float h0 = H[(size_t)p0.x * NCH + lane];
        float h1 = H[(size_t)p1.x * NCH + lane];
        float h2 = H[(size_t)p2.x * NCH + lane];
        float h3 = H[(size_t)p3.x * NCH + lane];
        a0 += __int_as_float(p0.y) * h0;
        a1 += __int_as_float(p1.y) * h1;
        a2 += __int_as_float(p2.y) * h2;
        a3 += __int_as_float(p3.y) * h3;
    }
    for (; e < end; e++) {
        int2 p = cpair[e];
        a0 += __int_as_float(p.y) * H[(size_t)p.x * NCH + lane];
    }
    float acc = (a0 + a1) + (a2 + a3);
    if (do_relu) acc = fmaxf(acc, 0.f);
    out[(size_t)node * NCH + lane] = acc;
}

extern "C" void kernel_launch(void* const* d_in, const int* in_sizes, int n_in,
                              void* d_out, int out_size, void* d_ws, size_t ws_size,
                              hipStream_t stream) {
    const float* x  = (const float*)d_in[0];
    const int* edge = (const int*)d_in[1];
    const float* W1 = (const float*)d_in[2];
    const float* b1 = (const float*)d_in[3];
    const float* W2 = (const float*)d_in[4];
    const float* b2 = (const float*)d_in[5];
    float* out = (float*)d_out;

    const int N = in_sizes[0] / NCH;       // 100000
    const int E = in_sizes[1] / 2;         // 1200000
    const int* src = edge;
    const int* dst = edge + E;

    // workspace layout (16B-aligned blocks)
    char* w = (char*)d_ws;
    const size_t SZN = 400128;             // >= (N+1)*4, padded
    int*   counts = (int*)(w + 0);
    int*   cursor = (int*)(w + SZN);
    int*   rowp   = (int*)(w + 2 * SZN);   // N+1 ints
    float* dinv   = (float*)(w + 3 * SZN);
    int*   bsums  = (int*)(w + 4 * SZN);   // 128 ints
    int2*  cpair  = (int2*)(w + 4 * SZN + 512);               // E pairs = 9.6 MB
    float* h      = (float*)(w + 4 * SZN + 512 + (size_t)E * 8);  // N*64 floats

    const int NB_SCAN = (N + 1023) / 1024;  // 98

    // 1) zero counts + cursor (contiguous 2*SZN bytes)
    hipMemsetAsync(counts, 0, 2 * SZN, stream);
    // 2) degree histogram over dst
    hist_kernel<<<(E + 255) / 256, 256, 0, stream>>>(dst, counts, E);
    // 3-5) exclusive scan counts -> rowp (dinv fused into scanA)
    scanA_kernel<<<NB_SCAN, 256, 0, stream>>>(counts, rowp, bsums, dinv, N);
    scanB_kernel<<<1, 128, 0, stream>>>(bsums, NB_SCAN);
    scanC_kernel<<<(N + 255) / 256, 256, 0, stream>>>(rowp, bsums, N);
    // 6) scatter into packed CSR
    scatter_kernel<<<(E + 255) / 256, 256, 0, stream>>>(src, dst, rowp, cursor, dinv,
                                                        cpair, E);

    const int GB = (N + 63) / 64;      // gemm blocks (64 rows each)
    const int AB = (N + 3) / 4;        // aggregate blocks (4 waves/block)

    // Layer 1: h = x@W1 ; d_out = relu(aggregate(h) + b1)   (d_out used as activation)
    gemm64_kernel<<<GB, 256, 0, stream>>>(x, W1, h, N);
    aggregate_kernel<<<AB, 256, 0, stream>>>(h, rowp, cpair, dinv, b1, out, N, 1);
    // Layer 2: h = act@W2 ; d_out = aggregate(h) + b2
    gemm64_kernel<<<GB, 256, 0, stream>>>(out, W2, h, N);
    aggregate_kernel<<<AB, 256, 0, stream>>>(h, rowp, cpair, dinv, b2, out, N, 0);
}

// Round 4
// 420.677 us; speedup vs baseline: 3.2989x; 3.2989x over previous
//
#include <hip/hip_runtime.h>

// GCN 2-layer: per layer h = X@W; out[i] = b + dinv[i]^2*h[i] + sum_{e:dst=i} dinv[src]*dinv[i]*h[src]
// N=100000 nodes, E=1200000 edges, C=64 channels, fp32 throughout.
// CSR-by-dst build (histogram + scan + scatter of PACKED (src,norm) int2 pairs),
// then gather-aggregate (wave per node, lane per channel). No float atomics.
// R4: gemm keeps the R3 64x64 tile / 4x4-per-thread structure but drops the
//     min-waves launch_bounds hint. R3's __launch_bounds__(256,4) squeezed the
//     allocator to 64 VGPR -> spill loop -> 1 GB scratch traffic/dispatch, 543us.
//     Natural allocation (~100 VGPR, 2-3 blocks/CU) beats forced-spill occupancy.

#define NCH 64
#define XS_STRIDE 68  // 64 + 4 pad: keeps b128 16B alignment; 4-row spacing -> bank+16 (2-way, free)

// counts[d] = #edges with dst==d
__global__ void hist_kernel(const int* __restrict__ dst, int* __restrict__ counts, int E) {
    int e = blockIdx.x * blockDim.x + threadIdx.x;
    if (e < E) atomicAdd(&counts[dst[e]], 1);
}

// ---------------- exclusive scan (3-phase), chunk = 1024; dinv fused ----------------
__global__ __launch_bounds__(256) void scanA_kernel(const int* __restrict__ counts,
                                                    int* __restrict__ rowp,
                                                    int* __restrict__ bsums,
                                                    float* __restrict__ dinv, int n) {
    __shared__ int sh[256];
    int tid = threadIdx.x;
    int base = blockIdx.x * 1024;
    int v[4];
    int ts = 0;
#pragma unroll
    for (int j = 0; j < 4; j++) {
        int idx = base + tid * 4 + j;
        int c = (idx < n) ? counts[idx] : 0;
        v[j] = c; ts += c;
        if (idx < n) dinv[idx] = rsqrtf((float)(c + 1));  // +1 self loop
    }
    sh[tid] = ts; __syncthreads();
    for (int off = 1; off < 256; off <<= 1) {
        int t = (tid >= off) ? sh[tid - off] : 0;
        __syncthreads();
        sh[tid] += t;
        __syncthreads();
    }
    int run = sh[tid] - ts;  // exclusive offset within chunk
#pragma unroll
    for (int j = 0; j < 4; j++) {
        run += v[j];
        int idx = base + tid * 4 + j;
        if (idx < n) rowp[idx + 1] = run;  // inclusive-within-chunk at [idx+1]
    }
    if (tid == 255) bsums[blockIdx.x] = sh[255];
}

__global__ __launch_bounds__(128) void scanB_kernel(int* __restrict__ bsums, int nb) {
    __shared__ int sh[128];
    int tid = threadIdx.x;
    int v = (tid < nb) ? bsums[tid] : 0;
    sh[tid] = v; __syncthreads();
    for (int off = 1; off < 128; off <<= 1) {
        int t = (tid >= off) ? sh[tid - off] : 0;
        __syncthreads();
        sh[tid] += t;
        __syncthreads();
    }
    if (tid < nb) bsums[tid] = sh[tid] - v;  // exclusive chunk offsets
}

__global__ void scanC_kernel(int* __restrict__ rowp, const int* __restrict__ bsums, int n) {
    int i = blockIdx.x * blockDim.x + threadIdx.x;
    if (i < n) {
        rowp[i + 1] += bsums[i >> 10];
        if (i == 0) rowp[0] = 0;
    }
}

// scatter edges into CSR buckets as packed (src, norm) pairs — single 8B store/edge
__global__ void scatter_kernel(const int* __restrict__ src, const int* __restrict__ dst,
                               const int* __restrict__ rowp, int* __restrict__ cursor,
                               const float* __restrict__ dinv,
                               int2* __restrict__ cpair, int E) {
    int e = blockIdx.x * blockDim.x + threadIdx.x;
    if (e < E) {
        int s = src[e], d = dst[e];
        int pos = rowp[d] + atomicAdd(&cursor[d], 1);
        cpair[pos] = make_int2(s, __float_as_int(dinv[s] * dinv[d]));
    }
}

// ---------------- H = X @ W  (K=64, fp32 VALU) ----------------
// 64x64 tile per block; 256 threads as 16x16; each thread: 4 rows x 4 cols (16 acc).
// Per k4-step: 4 b128 X reads + 4 b128 W reads per 64 FMAs.
// NOTE: no min-waves hint — R3's (256,4) forced VGPR=64 and a catastrophic spill loop.
__global__ __launch_bounds__(256) void gemm64_kernel(const float* __restrict__ X,
                                                     const float* __restrict__ W,
                                                     float* __restrict__ H, int nrows) {
    __shared__ float Xs[64 * XS_STRIDE];
    __shared__ float Ws[64 * 64];
    int tid = threadIdx.x;
    int row0 = blockIdx.x * 64;

    // stage W (4096 floats): 4 float4/thread, coalesced
    {
        const float4* W4 = (const float4*)W;
#pragma unroll
        for (int i = 0; i < 4; i++) {
            int idx = tid + 256 * i;           // float4 index
            float4 v = W4[idx];
            int r = idx >> 4, kc = (idx & 15) << 2;
            *(float4*)&Ws[r * 64 + kc] = v;
        }
    }
    // stage X tile (64 rows x 64): 4 float4/thread, coalesced; padded stride in LDS
    {
        const float4* X4 = (const float4*)(X + (size_t)row0 * NCH);
#pragma unroll
        for (int i = 0; i < 4; i++) {
            int idx = tid + 256 * i;
            int r = idx >> 4, kc = (idx & 15) << 2;
            if (row0 + r < nrows)
                *(float4*)&Xs[r * XS_STRIDE + kc] = X4[idx];
        }
    }
    __syncthreads();

    int c  = (tid & 15) << 2;   // col base
    int r0 = (tid >> 4) << 2;   // block-local row base

    float4 acc[4];
#pragma unroll
    for (int i = 0; i < 4; i++) acc[i] = make_float4(0.f, 0.f, 0.f, 0.f);

#pragma unroll
    for (int k4 = 0; k4 < 16; k4++) {
        float4 wv[4], xv[4];
#pragma unroll
        for (int j = 0; j < 4; j++) wv[j] = *(const float4*)&Ws[(k4 * 4 + j) * 64 + c];
#pragma unroll
        for (int i = 0; i < 4; i++) xv[i] = *(const float4*)&Xs[(r0 + i) * XS_STRIDE + k4 * 4];
#pragma unroll
        for (int i = 0; i < 4; i++) {
            acc[i].x += xv[i].x * wv[0].x + xv[i].y * wv[1].x + xv[i].z * wv[2].x + xv[i].w * wv[3].x;
            acc[i].y += xv[i].x * wv[0].y + xv[i].y * wv[1].y + xv[i].z * wv[2].y + xv[i].w * wv[3].y;
            acc[i].z += xv[i].x * wv[0].z + xv[i].y * wv[1].z + xv[i].z * wv[2].z + xv[i].w * wv[3].z;
            acc[i].w += xv[i].x * wv[0].w + xv[i].y * wv[1].w + xv[i].z * wv[2].w + xv[i].w * wv[3].w;
        }
    }

#pragma unroll
    for (int i = 0; i < 4; i++) {
        int row = row0 + r0 + i;
        if (row < nrows) *(float4*)&H[(size_t)row * NCH + c] = acc[i];
    }
}

// ---------------- gather-aggregate: wave per node, lane per channel ----------------
// unroll x4, 4 independent accumulators -> 4 gathers in flight
__global__ __launch_bounds__(256) void aggregate_kernel(const float* __restrict__ H,
                                                        const int* __restrict__ rowp,
                                                        const int2* __restrict__ cpair,
                                                        const float* __restrict__ dinv,
                                                        const float* __restrict__ bias,
                                                        float* __restrict__ out,
                                                        int n, int do_relu) {
    int node = blockIdx.x * 4 + (threadIdx.x >> 6);
    int lane = threadIdx.x & 63;
    if (node >= n) return;
    float di = dinv[node];
    float a0 = bias[lane] + di * di * H[(size_t)node * NCH + lane];
    float a1 = 0.f, a2 = 0.f, a3 = 0.f;
    int e = rowp[node];
    int end = rowp[node + 1];
    for (; e + 3 < end; e += 4) {
        int2 p0 = cpair[e];
        int2 p1 = cpair[e + 1];
        int2 p2 = cpair[e + 2];
        int2 p3 = cpair[e + 3];
        float h0 = H[(size_t)p0.x * NCH + lane];
        float h1 = H[(size_t)p1.x * NCH + lane];
        float h2 = H[(size_t)p2.x * NCH + lane];
        float h3 = H[(size_t)p3.x * NCH + lane];
        a0 += __int_as_float(p0.y) * h0;
        a1 += __int_as_float(p1.y) * h1;
        a2 += __int_as_float(p2.y) * h2;
        a3 += __int_as_float(p3.y) * h3;
    }
    for (; e < end; e++) {
        int2 p = cpair[e];
        a0 += __int_as_float(p.y) * H[(size_t)p.x * NCH + lane];
    }
    float acc = (a0 + a1) + (a2 + a3);
    if (do_relu) acc = fmaxf(acc, 0.f);
    out[(size_t)node * NCH + lane] = acc;
}

extern "C" void kernel_launch(void* const* d_in, const int* in_sizes, int n_in,
                              void* d_out, int out_size, void* d_ws, size_t ws_size,
                              hipStream_t stream) {
    const float* x  = (const float*)d_in[0];
    const int* edge = (const int*)d_in[1];
    const float* W1 = (const float*)d_in[2];
    const float* b1 = (const float*)d_in[3];
    const float* W2 = (const float*)d_in[4];
    const float* b2 = (const float*)d_in[5];
    float* out = (float*)d_out;

    const int N = in_sizes[0] / NCH;       // 100000
    const int E = in_sizes[1] / 2;         // 1200000
    const int* src = edge;
    const int* dst = edge + E;

    // workspace layout (16B-aligned blocks)
    char* w = (char*)d_ws;
    const size_t SZN = 400128;             // >= (N+1)*4, padded
    int*   counts = (int*)(w + 0);
    int*   cursor = (int*)(w + SZN);
    int*   rowp   = (int*)(w + 2 * SZN);   // N+1 ints
    float* dinv   = (float*)(w + 3 * SZN);
    int*   bsums  = (int*)(w + 4 * SZN);   // 128 ints
    int2*  cpair  = (int2*)(w + 4 * SZN + 512);               // E pairs = 9.6 MB
    float* h      = (float*)(w + 4 * SZN + 512 + (size_t)E * 8);  // N*64 floats

    const int NB_SCAN = (N + 1023) / 1024;  // 98

    // 1) zero counts + cursor (contiguous 2*SZN bytes)
    hipMemsetAsync(counts, 0, 2 * SZN, stream);
    // 2) degree histogram over dst
    hist_kernel<<<(E + 255) / 256, 256, 0, stream>>>(dst, counts, E);
    // 3-5) exclusive scan counts -> rowp (dinv fused into scanA)
    scanA_kernel<<<NB_SCAN, 256, 0, stream>>>(counts, rowp, bsums, dinv, N);
    scanB_kernel<<<1, 128, 0, stream>>>(bsums, NB_SCAN);
    scanC_kernel<<<(N + 255) / 256, 256, 0, stream>>>(rowp, bsums, N);
    // 6) scatter into packed CSR
    scatter_kernel<<<(E + 255) / 256, 256, 0, stream>>>(src, dst, rowp, cursor, dinv,
                                                        cpair, E);

    const int GB = (N + 63) / 64;      // gemm blocks (64 rows each)
    const int AB = (N + 3) / 4;        // aggregate blocks (4 waves/block)

    // Layer 1: h = x@W1 ; d_out = relu(aggregate(h) + b1)   (d_out used as activation)
    gemm64_kernel<<<GB, 256, 0, stream>>>(x, W1, h, N);
    aggregate_kernel<<<AB, 256, 0, stream>>>(h, rowp, cpair, dinv, b1, out, N, 1);
    // Layer 2: h = act@W2 ; d_out = aggregate(h) + b2
    gemm64_kernel<<<GB, 256, 0, stream>>>(out, W2, h, N);
    aggregate_kernel<<<AB, 256, 0, stream>>>(h, rowp, cpair, dinv, b2, out, N, 0);
}

// Round 5
// 337.933 us; speedup vs baseline: 4.1067x; 1.2449x over previous
//
#include <hip/hip_runtime.h>

// GCN 2-layer: per layer h = X@W; out[i] = b + dinv[i]^2*h[i] + sum_{e:dst=i} dinv[src]*dinv[i]*h[src]
// N=100000 nodes, E=1200000 edges, C=64 channels, fp32 throughout.
// CSR-by-dst build (histogram + scan + scatter of PACKED (src,norm) int2 pairs),
// then gather-aggregate (wave per node, lane per channel). No float atomics.
// R5: gemm k-loop unroll capped at 2 (R4: full unroll -> 256 VGPR, 9% occupancy,
//     63us; roofline ~12us). aggregate gather depth 4 -> 8 outstanding loads
//     (latency-bound at 8 B/cy/CU, well under L2 BW).

#define NCH 64
#define XS_STRIDE 68  // 64 + 4 pad: keeps b128 16B alignment; 4-row spacing -> bank+16 (2-way, free)

// counts[d] = #edges with dst==d
__global__ void hist_kernel(const int* __restrict__ dst, int* __restrict__ counts, int E) {
    int e = blockIdx.x * blockDim.x + threadIdx.x;
    if (e < E) atomicAdd(&counts[dst[e]], 1);
}

// ---------------- exclusive scan (3-phase), chunk = 1024; dinv fused ----------------
__global__ __launch_bounds__(256) void scanA_kernel(const int* __restrict__ counts,
                                                    int* __restrict__ rowp,
                                                    int* __restrict__ bsums,
                                                    float* __restrict__ dinv, int n) {
    __shared__ int sh[256];
    int tid = threadIdx.x;
    int base = blockIdx.x * 1024;
    int v[4];
    int ts = 0;
#pragma unroll
    for (int j = 0; j < 4; j++) {
        int idx = base + tid * 4 + j;
        int c = (idx < n) ? counts[idx] : 0;
        v[j] = c; ts += c;
        if (idx < n) dinv[idx] = rsqrtf((float)(c + 1));  // +1 self loop
    }
    sh[tid] = ts; __syncthreads();
    for (int off = 1; off < 256; off <<= 1) {
        int t = (tid >= off) ? sh[tid - off] : 0;
        __syncthreads();
        sh[tid] += t;
        __syncthreads();
    }
    int run = sh[tid] - ts;  // exclusive offset within chunk
#pragma unroll
    for (int j = 0; j < 4; j++) {
        run += v[j];
        int idx = base + tid * 4 + j;
        if (idx < n) rowp[idx + 1] = run;  // inclusive-within-chunk at [idx+1]
    }
    if (tid == 255) bsums[blockIdx.x] = sh[255];
}

__global__ __launch_bounds__(128) void scanB_kernel(int* __restrict__ bsums, int nb) {
    __shared__ int sh[128];
    int tid = threadIdx.x;
    int v = (tid < nb) ? bsums[tid] : 0;
    sh[tid] = v; __syncthreads();
    for (int off = 1; off < 128; off <<= 1) {
        int t = (tid >= off) ? sh[tid - off] : 0;
        __syncthreads();
        sh[tid] += t;
        __syncthreads();
    }
    if (tid < nb) bsums[tid] = sh[tid] - v;  // exclusive chunk offsets
}

__global__ void scanC_kernel(int* __restrict__ rowp, const int* __restrict__ bsums, int n) {
    int i = blockIdx.x * blockDim.x + threadIdx.x;
    if (i < n) {
        rowp[i + 1] += bsums[i >> 10];
        if (i == 0) rowp[0] = 0;
    }
}

// scatter edges into CSR buckets as packed (src, norm) pairs — single 8B store/edge
__global__ void scatter_kernel(const int* __restrict__ src, const int* __restrict__ dst,
                               const int* __restrict__ rowp, int* __restrict__ cursor,
                               const float* __restrict__ dinv,
                               int2* __restrict__ cpair, int E) {
    int e = blockIdx.x * blockDim.x + threadIdx.x;
    if (e < E) {
        int s = src[e], d = dst[e];
        int pos = rowp[d] + atomicAdd(&cursor[d], 1);
        cpair[pos] = make_int2(s, __float_as_int(dinv[s] * dinv[d]));
    }
}

// ---------------- H = X @ W  (K=64, fp32 VALU) ----------------
// 64x64 tile per block; 256 threads as 16x16; each thread: 4 rows x 4 cols (16 acc).
// k-loop unroll capped at 2: full unroll hoists all 32 ds_read_b128 -> 256 VGPR
// (R4 evidence); unroll 2 keeps live set ~100 VGPR for 4 waves/SIMD.
__global__ __launch_bounds__(256) void gemm64_kernel(const float* __restrict__ X,
                                                     const float* __restrict__ W,
                                                     float* __restrict__ H, int nrows) {
    __shared__ float Xs[64 * XS_STRIDE];
    __shared__ float Ws[64 * 64];
    int tid = threadIdx.x;
    int row0 = blockIdx.x * 64;

    // stage W (4096 floats): 4 float4/thread, coalesced
    {
        const float4* W4 = (const float4*)W;
#pragma unroll
        for (int i = 0; i < 4; i++) {
            int idx = tid + 256 * i;           // float4 index
            float4 v = W4[idx];
            int r = idx >> 4, kc = (idx & 15) << 2;
            *(float4*)&Ws[r * 64 + kc] = v;
        }
    }
    // stage X tile (64 rows x 64): 4 float4/thread, coalesced; padded stride in LDS
    {
        const float4* X4 = (const float4*)(X + (size_t)row0 * NCH);
#pragma unroll
        for (int i = 0; i < 4; i++) {
            int idx = tid + 256 * i;
            int r = idx >> 4, kc = (idx & 15) << 2;
            if (row0 + r < nrows)
                *(float4*)&Xs[r * XS_STRIDE + kc] = X4[idx];
        }
    }
    __syncthreads();

    int c  = (tid & 15) << 2;   // col base
    int r0 = (tid >> 4) << 2;   // block-local row base

    float4 acc[4];
#pragma unroll
    for (int i = 0; i < 4; i++) acc[i] = make_float4(0.f, 0.f, 0.f, 0.f);

#pragma unroll 2
    for (int k4 = 0; k4 < 16; k4++) {
        float4 wv[4], xv[4];
#pragma unroll
        for (int j = 0; j < 4; j++) wv[j] = *(const float4*)&Ws[(k4 * 4 + j) * 64 + c];
#pragma unroll
        for (int i = 0; i < 4; i++) xv[i] = *(const float4*)&Xs[(r0 + i) * XS_STRIDE + k4 * 4];
#pragma unroll
        for (int i = 0; i < 4; i++) {
            acc[i].x += xv[i].x * wv[0].x + xv[i].y * wv[1].x + xv[i].z * wv[2].x + xv[i].w * wv[3].x;
            acc[i].y += xv[i].x * wv[0].y + xv[i].y * wv[1].y + xv[i].z * wv[2].y + xv[i].w * wv[3].y;
            acc[i].z += xv[i].x * wv[0].z + xv[i].y * wv[1].z + xv[i].z * wv[2].z + xv[i].w * wv[3].z;
            acc[i].w += xv[i].x * wv[0].w + xv[i].y * wv[1].w + xv[i].z * wv[2].w + xv[i].w * wv[3].w;
        }
    }

#pragma unroll
    for (int i = 0; i < 4; i++) {
        int row = row0 + r0 + i;
        if (row < nrows) *(float4*)&H[(size_t)row * NCH + c] = acc[i];
    }
}

// ---------------- gather-aggregate: wave per node, lane per channel ----------------
// 8 outstanding gathers (latency-bound loop; mean degree 12 -> one 8-batch + one 4-batch)
__global__ __launch_bounds__(256) void aggregate_kernel(const float* __restrict__ H,
                                                        const int* __restrict__ rowp,
                                                        const int2* __restrict__ cpair,
                                                        const float* __restrict__ dinv,
                                                        const float* __restrict__ bias,
                                                        float* __restrict__ out,
                                                        int n, int do_relu) {
    int node = blockIdx.x * 4 + (threadIdx.x >> 6);
    int lane = threadIdx.x & 63;
    if (node >= n) return;
    float di = dinv[node];
    float a0 = bias[lane] + di * di * H[(size_t)node * NCH + lane];
    float a1 = 0.f, a2 = 0.f, a3 = 0.f;
    float a4 = 0.f, a5 = 0.f, a6 = 0.f, a7 = 0.f;
    int e = rowp[node];
    int end = rowp[node + 1];
    for (; e + 7 < end; e += 8) {
        int2 p0 = cpair[e];
        int2 p1 = cpair[e + 1];
        int2 p2 = cpair[e + 2];
        int2 p3 = cpair[e + 3];
        int2 p4 = cpair[e + 4];
        int2 p5 = cpair[e + 5];
        int2 p6 = cpair[e + 6];
        int2 p7 = cpair[e + 7];
        float h0 = H[(size_t)p0.x * NCH + lane];
        float h1 = H[(size_t)p1.x * NCH + lane];
        float h2 = H[(size_t)p2.x * NCH + lane];
        float h3 = H[(size_t)p3.x * NCH + lane];
        float h4 = H[(size_t)p4.x * NCH + lane];
        float h5 = H[(size_t)p5.x * NCH + lane];
        float h6 = H[(size_t)p6.x * NCH + lane];
        float h7 = H[(size_t)p7.x * NCH + lane];
        a0 += __int_as_float(p0.y) * h0;
        a1 += __int_as_float(p1.y) * h1;
        a2 += __int_as_float(p2.y) * h2;
        a3 += __int_as_float(p3.y) * h3;
        a4 += __int_as_float(p4.y) * h4;
        a5 += __int_as_float(p5.y) * h5;
        a6 += __int_as_float(p6.y) * h6;
        a7 += __int_as_float(p7.y) * h7;
    }
    if (e + 3 < end) {
        int2 p0 = cpair[e];
        int2 p1 = cpair[e + 1];
        int2 p2 = cpair[e + 2];
        int2 p3 = cpair[e + 3];
        float h0 = H[(size_t)p0.x * NCH + lane];
        float h1 = H[(size_t)p1.x * NCH + lane];
        float h2 = H[(size_t)p2.x * NCH + lane];
        float h3 = H[(size_t)p3.x * NCH + lane];
        a0 += __int_as_float(p0.y) * h0;
        a1 += __int_as_float(p1.y) * h1;
        a2 += __int_as_float(p2.y) * h2;
        a3 += __int_as_float(p3.y) * h3;
        e += 4;
    }
    for (; e < end; e++) {
        int2 p = cpair[e];
        a0 += __int_as_float(p.y) * H[(size_t)p.x * NCH + lane];
    }
    float acc = ((a0 + a1) + (a2 + a3)) + ((a4 + a5) + (a6 + a7));
    if (do_relu) acc = fmaxf(acc, 0.f);
    out[(size_t)node * NCH + lane] = acc;
}

extern "C" void kernel_launch(void* const* d_in, const int* in_sizes, int n_in,
                              void* d_out, int out_size, void* d_ws, size_t ws_size,
                              hipStream_t stream) {
    const float* x  = (const float*)d_in[0];
    const int* edge = (const int*)d_in[1];
    const float* W1 = (const float*)d_in[2];
    const float* b1 = (const float*)d_in[3];
    const float* W2 = (const float*)d_in[4];
    const float* b2 = (const float*)d_in[5];
    float* out = (float*)d_out;

    const int N = in_sizes[0] / NCH;       // 100000
    const int E = in_sizes[1] / 2;         // 1200000
    const int* src = edge;
    const int* dst = edge + E;

    // workspace layout (16B-aligned blocks)
    char* w = (char*)d_ws;
    const size_t SZN = 400128;             // >= (N+1)*4, padded
    int*   counts = (int*)(w + 0);
    int*   cursor = (int*)(w + SZN);
    int*   rowp   = (int*)(w + 2 * SZN);   // N+1 ints
    float* dinv   = (float*)(w + 3 * SZN);
    int*   bsums  = (int*)(w + 4 * SZN);   // 128 ints
    int2*  cpair  = (int2*)(w + 4 * SZN + 512);               // E pairs = 9.6 MB
    float* h      = (float*)(w + 4 * SZN + 512 + (size_t)E * 8);  // N*64 floats

    const int NB_SCAN = (N + 1023) / 1024;  // 98

    // 1) zero counts + cursor (contiguous 2*SZN bytes)
    hipMemsetAsync(counts, 0, 2 * SZN, stream);
    // 2) degree histogram over dst
    hist_kernel<<<(E + 255) / 256, 256, 0, stream>>>(dst, counts, E);
    // 3-5) exclusive scan counts -> rowp (dinv fused into scanA)
    scanA_kernel<<<NB_SCAN, 256, 0, stream>>>(counts, rowp, bsums, dinv, N);
    scanB_kernel<<<1, 128, 0, stream>>>(bsums, NB_SCAN);
    scanC_kernel<<<(N + 255) / 256, 256, 0, stream>>>(rowp, bsums, N);
    // 6) scatter into packed CSR
    scatter_kernel<<<(E + 255) / 256, 256, 0, stream>>>(src, dst, rowp, cursor, dinv,
                                                        cpair, E);

    const int GB = (N + 63) / 64;      // gemm blocks (64 rows each)
    const int AB = (N + 3) / 4;        // aggregate blocks (4 waves/block)

    // Layer 1: h = x@W1 ; d_out = relu(aggregate(h) + b1)   (d_out used as activation)
    gemm64_kernel<<<GB, 256, 0, stream>>>(x, W1, h, N);
    aggregate_kernel<<<AB, 256, 0, stream>>>(h, rowp, cpair, dinv, b1, out, N, 1);
    // Layer 2: h = act@W2 ; d_out = aggregate(h) + b2
    gemm64_kernel<<<GB, 256, 0, stream>>>(out, W2, h, N);
    aggregate_kernel<<<AB, 256, 0, stream>>>(h, rowp, cpair, dinv, b2, out, N, 0);
}